// Round 2
// baseline (194.573 us; speedup 1.0000x reference)
//
#include <hip/hip_runtime.h>

// cyclicLoss: out = mean((input-target)^2) + 0.1*sqrt( sum_{i<(N-1)*T} (input[i]-input[i+T])^2 )
// fp32, n = N*T = 2048*8192 = 16.8M elements (64 MB each array).
//
// R1 design: column-walk. Thread owns float4-column `col` and rows [r0, r0+16):
//   - input element loaded ONCE serves both the mse term and both sides of the
//     cyclic diff (x[row] - x[row+1]) -> logical traffic 192 MB -> ~132 MB.
//   - 16 rows fully unrolled -> ~33 independent global loads in flight/thread
//     (fixes the latency-bound 11%-of-HBM profile of R0).
//   - last-block ticket finalizes in the same kernel (one dispatch + 4B memset).

#define LAMDA 0.1
#define ROWS 16
#define BLOCK 256

__global__ __launch_bounds__(BLOCK) void cyclic_fused_kernel(
    const float4* __restrict__ in4,
    const float4* __restrict__ tg4,
    const int* __restrict__ pT,
    const int* __restrict__ pN,
    long long n,
    double* __restrict__ m_part,      // [gridDim.x]
    double* __restrict__ d_part,      // [gridDim.x]
    unsigned int* __restrict__ counter,
    float* __restrict__ out)
{
    const int T = pT[0];
    const int N = pN[0];
    const long long t4 = (long long)T >> 2;                    // float4 columns
    const long long segs = ((long long)N + ROWS - 1) / ROWS;
    const long long W = t4 * segs;                             // work items

    float mse_acc = 0.0f;
    float dif_acc = 0.0f;

    const long long gtid = (long long)blockIdx.x * BLOCK + threadIdx.x;
    const long long stride = (long long)gridDim.x * BLOCK;

    for (long long w = gtid; w < W; w += stride) {
        const long long col = w % t4;
        const long long seg = w / t4;
        const int r0 = (int)(seg * ROWS);
        const float4* pin = in4 + (long long)r0 * t4 + col;
        const float4* ptg = tg4 + (long long)r0 * t4 + col;

        float4 xa[ROWS + 1];
        // load input column segment + target, accumulate mse immediately
        #pragma unroll
        for (int k = 0; k < ROWS; ++k) {
            if (r0 + k < N) {
                xa[k] = pin[(long long)k * t4];
                float4 b = ptg[(long long)k * t4];
                float e0 = xa[k].x - b.x, e1 = xa[k].y - b.y;
                float e2 = xa[k].z - b.z, e3 = xa[k].w - b.w;
                mse_acc += e0 * e0 + e1 * e1 + e2 * e2 + e3 * e3;
            }
        }
        if (r0 + ROWS < N) xa[ROWS] = pin[(long long)ROWS * t4];

        // cyclic diff: rows r0..r0+ROWS-1 against the next row
        #pragma unroll
        for (int k = 0; k < ROWS; ++k) {
            if (r0 + k + 1 < N) {
                float4 a = xa[k], c = xa[k + 1];
                float d0 = a.x - c.x, d1 = a.y - c.y;
                float d2 = a.z - c.z, d3 = a.w - c.w;
                dif_acc += d0 * d0 + d1 * d1 + d2 * d2 + d3 * d3;
            }
        }
    }

    // mse over any region beyond N*T (none for this shape, kept for generality)
    {
        const long long nt4 = ((long long)N * T) >> 2;
        const long long n4 = n >> 2;
        for (long long i = nt4 + gtid; i < n4; i += stride) {
            float4 a = in4[i], b = tg4[i];
            float e0 = a.x - b.x, e1 = a.y - b.y, e2 = a.z - b.z, e3 = a.w - b.w;
            mse_acc += e0 * e0 + e1 * e1 + e2 * e2 + e3 * e3;
        }
        // scalar tail (n % 4)
        const long long tail = (n4 << 2) + gtid;
        if (tail < n) {
            float e = ((const float*)in4)[tail] - ((const float*)tg4)[tail];
            mse_acc += e * e;
        }
    }

    // ---- block reduction (wave-64 shuffle, then LDS across 4 waves) ----
    #pragma unroll
    for (int off = 32; off > 0; off >>= 1) {
        mse_acc += __shfl_down(mse_acc, off, 64);
        dif_acc += __shfl_down(dif_acc, off, 64);
    }
    __shared__ float s_m[4], s_d[4];
    const int wave = threadIdx.x >> 6;
    if ((threadIdx.x & 63) == 0) { s_m[wave] = mse_acc; s_d[wave] = dif_acc; }
    __syncthreads();

    __shared__ bool isLast;
    if (threadIdx.x == 0) {
        double m = (double)s_m[0] + (double)s_m[1] + (double)s_m[2] + (double)s_m[3];
        double d = (double)s_d[0] + (double)s_d[1] + (double)s_d[2] + (double)s_d[3];
        m_part[blockIdx.x] = m;
        d_part[blockIdx.x] = d;
        __threadfence();                       // make partials visible device-wide
        unsigned int old = atomicAdd(counter, 1u);
        isLast = (old == gridDim.x - 1);
    }
    __syncthreads();

    // ---- last block finalizes ----
    if (isLast) {
        __threadfence();                       // acquire partials from all XCDs
        double m = 0.0, d = 0.0;
        for (int i = threadIdx.x; i < (int)gridDim.x; i += BLOCK) {
            m += m_part[i];
            d += d_part[i];
        }
        #pragma unroll
        for (int off = 32; off > 0; off >>= 1) {
            m += __shfl_down(m, off, 64);
            d += __shfl_down(d, off, 64);
        }
        __shared__ double f_m[4], f_d[4];
        if ((threadIdx.x & 63) == 0) { f_m[wave] = m; f_d[wave] = d; }
        __syncthreads();
        if (threadIdx.x == 0) {
            double mt = f_m[0] + f_m[1] + f_m[2] + f_m[3];
            double dt = f_d[0] + f_d[1] + f_d[2] + f_d[3];
            double mse = mt / (double)n;
            double nom = (N != 1) ? (LAMDA * sqrt(dt)) : 0.0;
            out[0] = (float)(mse + nom);
        }
    }
}

extern "C" void kernel_launch(void* const* d_in, const int* in_sizes, int n_in,
                              void* d_out, int out_size, void* d_ws, size_t ws_size,
                              hipStream_t stream) {
    const float* input  = (const float*)d_in[0];
    const float* target = (const float*)d_in[1];
    const int*   pT     = (const int*)d_in[2];
    const int*   pN     = (const int*)d_in[3];
    float* out = (float*)d_out;

    const long long n = (long long)in_sizes[0];

    const int grid = 1024;   // 2048 cols * 128 segs = 256K items = grid*BLOCK exactly
    double* m_part = (double*)d_ws;
    double* d_part = m_part + grid;
    unsigned int* counter = (unsigned int*)(d_part + grid);

    // only the ticket counter needs zeroing (partials are written unconditionally)
    hipMemsetAsync(counter, 0, sizeof(unsigned int), stream);

    cyclic_fused_kernel<<<grid, BLOCK, 0, stream>>>(
        (const float4*)input, (const float4*)target, pT, pN, n,
        m_part, d_part, counter, out);
}